// Round 6
// baseline (2782.417 us; speedup 1.0000x reference)
//
#include <hip/hip_runtime.h>
#include <cstdint>

#define BB 256
#define TT 1000
#define DD 256
#define SS 10
#define HH 64
#define CC 100

// ---------------------------------------------------------------------------
// Kernel 1: input projection  xp[b,t,h] = 2*(x . W_ih + b_ih + b_hh)
// (2x pre-scale feeds tanh's exp(2z) so the rnn chain skips one multiply)
// ---------------------------------------------------------------------------
__global__ __launch_bounds__(256) void proj_kernel(
    const float* __restrict__ x, const float* __restrict__ W_ih,
    const float* __restrict__ b_ih, const float* __restrict__ b_hh,
    float* __restrict__ xp) {
  __shared__ float As[64][68];
  __shared__ float Bs[64][68];
  const int s = blockIdx.y;
  const int r0 = blockIdx.x * 64;
  const int tid = threadIdx.x;
  const int ty = tid >> 4, tx = tid & 15;
  const int ty4 = ty * 4, tx4 = tx * 4;
  float acc[4][4] = {{0.f, 0.f, 0.f, 0.f}};

  for (int kc = 0; kc < 4; ++kc) {
#pragma unroll
    for (int m = 0; m < 4; ++m) {
      int f = m * 256 + tid;
      int row = f >> 4, kq = f & 15;
      int r = r0 + row;
      int b = r / CC, c = r - b * CC;
      const float4 av = *(const float4*)(
          x + ((size_t)b * TT + s * CC + c) * DD + kc * 64 + kq * 4);
      *(float4*)&As[row][kq * 4] = av;
      const float4 wv = *(const float4*)(
          W_ih + ((size_t)s * HH + row) * DD + kc * 64 + kq * 4);
      *(float4*)&Bs[row][kq * 4] = wv;
    }
    __syncthreads();
#pragma unroll 4
    for (int k = 0; k < 64; k += 4) {
      float4 a[4], w[4];
#pragma unroll
      for (int i = 0; i < 4; ++i) a[i] = *(const float4*)&As[ty4 + i][k];
#pragma unroll
      for (int j = 0; j < 4; ++j) w[j] = *(const float4*)&Bs[tx4 + j][k];
#pragma unroll
      for (int i = 0; i < 4; ++i)
#pragma unroll
        for (int j = 0; j < 4; ++j)
          acc[i][j] += a[i].x * w[j].x + a[i].y * w[j].y +
                       a[i].z * w[j].z + a[i].w * w[j].w;
    }
    __syncthreads();
  }

  const float4 b1 = *(const float4*)(b_ih + s * HH + tx4);
  const float4 b2 = *(const float4*)(b_hh + s * HH + tx4);
#pragma unroll
  for (int i = 0; i < 4; ++i) {
    int r = r0 + ty4 + i;
    int b = r / CC, c = r - b * CC;
    float4 o;
    o.x = 2.f * (acc[i][0] + b1.x + b2.x);
    o.y = 2.f * (acc[i][1] + b1.y + b2.y);
    o.z = 2.f * (acc[i][2] + b1.z + b2.z);
    o.w = 2.f * (acc[i][3] + b1.w + b2.w);
    *(float4*)(xp + ((size_t)b * TT + s * CC + c) * HH + tx4) = o;
  }
}

// ---------------------------------------------------------------------------
// Kernel 2 (REAL): R4 bpermute structure + prescaled W/xp (z2 direct).
// Best-known correct rnn (302 us in R4).
// ---------------------------------------------------------------------------
__global__ __launch_bounds__(64, 1) void rnn_real(
    const float* __restrict__ xp, const float* __restrict__ W_hh,
    const float* __restrict__ fc_w, const float* __restrict__ fc_b,
    float* __restrict__ y) {
  __shared__ float hist[CC][68];
  const int b = blockIdx.x;
  const int lane = threadIdx.x;

  float W[64];
  float h = 0.f;
  for (int s = 0; s < SS; ++s) {
    const float* wr = W_hh + ((size_t)s * HH + lane) * HH;
#pragma unroll
    for (int j = 0; j < 64; j += 4) {
      float4 v = *(const float4*)(wr + j);
      W[j] = 2.f * v.x; W[j + 1] = 2.f * v.y;
      W[j + 2] = 2.f * v.z; W[j + 3] = 2.f * v.w;
    }
    const float* xps = xp + ((size_t)b * TT + s * CC) * HH + lane;

    float xq0 = xps[0 * HH];
    float xq1 = xps[1 * HH];
    float xq2 = xps[2 * HH];
    float xq3 = xps[3 * HH];

    for (int c4 = 0; c4 < 25; ++c4) {
#pragma unroll
      for (int u = 0; u < 4; ++u) {
        const int c = c4 * 4 + u;
        const float xv = (u == 0) ? xq0 : (u == 1) ? xq1 : (u == 2) ? xq2 : xq3;
        const int hu = __float_as_int(h);
        float a0 = xv, a1 = 0.f, a2 = 0.f, a3 = 0.f;
#pragma unroll
        for (int j = 0; j < 64; j += 4) {
          float h0 = __int_as_float(__builtin_amdgcn_ds_bpermute((j + 0) * 4, hu));
          float h1 = __int_as_float(__builtin_amdgcn_ds_bpermute((j + 1) * 4, hu));
          float h2 = __int_as_float(__builtin_amdgcn_ds_bpermute((j + 2) * 4, hu));
          float h3 = __int_as_float(__builtin_amdgcn_ds_bpermute((j + 3) * 4, hu));
          a0 += W[j + 0] * h0;
          a1 += W[j + 1] * h1;
          a2 += W[j + 2] * h2;
          a3 += W[j + 3] * h3;
        }
        float z2 = (a0 + a1) + (a2 + a3);  // = 2z (prescaled)
        float e = __expf(z2);
        h = 1.f - 2.f * __builtin_amdgcn_rcpf(e + 1.f);
        hist[c][lane] = h;
        if (c4 < 24) {
          const float xn = xps[(c + 4) * HH];
          if (u == 0) xq0 = xn;
          else if (u == 1) xq1 = xn;
          else if (u == 2) xq2 = xn;
          else xq3 = xn;
        }
      }
    }

    const float fb = fc_b[s];
    const float* fw = fc_w + s * HH;
#pragma unroll
    for (int base = 0; base < CC; base += 64) {
      int l = base + lane;
      if (l < CC) {
        float z = fb;
#pragma unroll
        for (int i = 0; i < 64; i += 4) {
          float4 hv = *(const float4*)&hist[l][i];
          z += hv.x * fw[i] + hv.y * fw[i + 1] + hv.z * fw[i + 2] +
               hv.w * fw[i + 3];
        }
        y[(size_t)b * TT + s * CC + l] =
            __builtin_amdgcn_rcpf(1.f + __expf(-z));
      }
    }
  }
}

// ---------------------------------------------------------------------------
// TIMING PROBES (diagnostic ablation; outputs go to scratch, 3x repeats).
// MODE 0: full LDS-broadcast step (R5 minus sched_barrier) - baseline B
// MODE 1: no tanh (h = z2 * 2^-7, chain kept live)         - probe C
// MODE 2: hist reads only every 4th step (stale h)          - probe D
// MODE 3: no xp global loads (xv = const)                   - probe E
// ---------------------------------------------------------------------------
template <int MODE>
__global__ __launch_bounds__(64, 1) void rnn_probe(
    const float* __restrict__ xp, const float* __restrict__ W_hh,
    float* __restrict__ out) {
  __shared__ float hist[CC][68];
  const int b = blockIdx.x;
  const int lane = threadIdx.x;
  hist[CC - 1][lane] = 0.f;

  float W[64];
  float h = 0.f;
  float4 hv[16];
  for (int rep = 0; rep < 3; ++rep) {
    for (int s = 0; s < SS; ++s) {
      const float* wr = W_hh + ((size_t)s * HH + lane) * HH;
#pragma unroll
      for (int j = 0; j < 64; j += 4) {
        float4 v = *(const float4*)(wr + j);
        W[j] = 2.f * v.x; W[j + 1] = 2.f * v.y;
        W[j + 2] = 2.f * v.z; W[j + 3] = 2.f * v.w;
      }
      const float* xps = xp + ((size_t)b * TT + s * CC) * HH + lane;

      float xq0, xq1, xq2, xq3;
      if constexpr (MODE != 3) {
        xq0 = xps[0 * HH]; xq1 = xps[1 * HH];
        xq2 = xps[2 * HH]; xq3 = xps[3 * HH];
      } else {
        xq0 = xq1 = xq2 = xq3 = 0.01f;
      }

      for (int c4 = 0; c4 < 25; ++c4) {
#pragma unroll
        for (int u = 0; u < 4; ++u) {
          const int c = c4 * 4 + u;
          const int cp = (c == 0) ? CC - 1 : c - 1;
          const float xv = (u == 0) ? xq0 : (u == 1) ? xq1 : (u == 2) ? xq2 : xq3;
          if constexpr (MODE == 2) {
            if (u == 0) {
#pragma unroll
              for (int j4 = 0; j4 < 16; ++j4)
                hv[j4] = *(const float4*)&hist[cp][j4 * 4];
            }
          } else {
#pragma unroll
            for (int j4 = 0; j4 < 16; ++j4)
              hv[j4] = *(const float4*)&hist[cp][j4 * 4];
          }
          float a0 = xv, a1 = 0.f, a2 = 0.f, a3 = 0.f;
#pragma unroll
          for (int j4 = 0; j4 < 16; ++j4) {
            a0 += W[j4 * 4 + 0] * hv[j4].x;
            a1 += W[j4 * 4 + 1] * hv[j4].y;
            a2 += W[j4 * 4 + 2] * hv[j4].z;
            a3 += W[j4 * 4 + 3] * hv[j4].w;
          }
          float z2 = (a0 + a1) + (a2 + a3);
          if constexpr (MODE == 1) {
            h = z2 * 0.0078125f;  // keep chain live, no transcendentals
          } else {
            float e = __expf(z2);
            h = 1.f - 2.f * __builtin_amdgcn_rcpf(e + 1.f);
          }
          hist[c][lane] = h;
          if constexpr (MODE != 3) {
            if (c4 < 24) {
              const float xn = xps[(c + 4) * HH];
              if (u == 0) xq0 = xn;
              else if (u == 1) xq1 = xn;
              else if (u == 2) xq2 = xn;
              else xq3 = xn;
            }
          }
        }
      }
    }
  }
  // keep-alive: fold hist + h into scratch
  float acc = h;
  for (int l = 0; l < CC; ++l) acc += hist[l][lane];
  out[(size_t)b * HH + lane] = acc;
}

extern "C" void kernel_launch(void* const* d_in, const int* in_sizes, int n_in,
                              void* d_out, int out_size, void* d_ws,
                              size_t ws_size, hipStream_t stream) {
  const float* x    = (const float*)d_in[0];
  const float* W_ih = (const float*)d_in[1];
  const float* W_hh = (const float*)d_in[2];
  const float* b_ih = (const float*)d_in[3];
  const float* b_hh = (const float*)d_in[4];
  const float* fc_w = (const float*)d_in[5];
  const float* fc_b = (const float*)d_in[6];
  float* y  = (float*)d_out;
  float* xp = (float*)d_ws;  // [B][T][H] fp32 = 65.5 MB

  proj_kernel<<<dim3(400, 10), 256, 0, stream>>>(x, W_ih, b_ih, b_hh, xp);
  rnn_real<<<256, 64, 0, stream>>>(xp, W_hh, fc_w, fc_b, y);

  // diagnostic probes (write into xp scratch; proj regenerates it each call)
  rnn_probe<0><<<256, 64, 0, stream>>>(xp, W_hh, xp + 1 * 16384);
  rnn_probe<1><<<256, 64, 0, stream>>>(xp, W_hh, xp + 2 * 16384);
  rnn_probe<2><<<256, 64, 0, stream>>>(xp, W_hh, xp + 3 * 16384);
  rnn_probe<3><<<256, 64, 0, stream>>>(xp, W_hh, xp + 4 * 16384);
}

// Round 7
// 445.376 us; speedup vs baseline: 6.2473x; 6.2473x over previous
//
#include <hip/hip_runtime.h>
#include <cstdint>

#define BB 256
#define TT 1000
#define DD 256
#define SS 10
#define HH 64
#define CC 100

// ---------------------------------------------------------------------------
// Kernel 1: input projection  xp[b,t,h] = 2*(x . W_ih + b_ih + b_hh)
// (2x pre-scale feeds tanh's exp(2z) so the rnn chain skips one multiply)
// ---------------------------------------------------------------------------
__global__ __launch_bounds__(256) void proj_kernel(
    const float* __restrict__ x, const float* __restrict__ W_ih,
    const float* __restrict__ b_ih, const float* __restrict__ b_hh,
    float* __restrict__ xp) {
  __shared__ float As[64][68];
  __shared__ float Bs[64][68];
  const int s = blockIdx.y;
  const int r0 = blockIdx.x * 64;
  const int tid = threadIdx.x;
  const int ty = tid >> 4, tx = tid & 15;
  const int ty4 = ty * 4, tx4 = tx * 4;
  float acc[4][4] = {{0.f, 0.f, 0.f, 0.f}};

  for (int kc = 0; kc < 4; ++kc) {
#pragma unroll
    for (int m = 0; m < 4; ++m) {
      int f = m * 256 + tid;
      int row = f >> 4, kq = f & 15;
      int r = r0 + row;
      int b = r / CC, c = r - b * CC;
      const float4 av = *(const float4*)(
          x + ((size_t)b * TT + s * CC + c) * DD + kc * 64 + kq * 4);
      *(float4*)&As[row][kq * 4] = av;
      const float4 wv = *(const float4*)(
          W_ih + ((size_t)s * HH + row) * DD + kc * 64 + kq * 4);
      *(float4*)&Bs[row][kq * 4] = wv;
    }
    __syncthreads();
#pragma unroll 4
    for (int k = 0; k < 64; k += 4) {
      float4 a[4], w[4];
#pragma unroll
      for (int i = 0; i < 4; ++i) a[i] = *(const float4*)&As[ty4 + i][k];
#pragma unroll
      for (int j = 0; j < 4; ++j) w[j] = *(const float4*)&Bs[tx4 + j][k];
#pragma unroll
      for (int i = 0; i < 4; ++i)
#pragma unroll
        for (int j = 0; j < 4; ++j)
          acc[i][j] += a[i].x * w[j].x + a[i].y * w[j].y +
                       a[i].z * w[j].z + a[i].w * w[j].w;
    }
    __syncthreads();
  }

  const float4 b1 = *(const float4*)(b_ih + s * HH + tx4);
  const float4 b2 = *(const float4*)(b_hh + s * HH + tx4);
#pragma unroll
  for (int i = 0; i < 4; ++i) {
    int r = r0 + ty4 + i;
    int b = r / CC, c = r - b * CC;
    float4 o;
    o.x = 2.f * (acc[i][0] + b1.x + b2.x);
    o.y = 2.f * (acc[i][1] + b1.y + b2.y);
    o.z = 2.f * (acc[i][2] + b1.z + b2.z);
    o.w = 2.f * (acc[i][3] + b1.w + b2.w);
    *(float4*)(xp + ((size_t)b * TT + s * CC + c) * HH + tx4) = o;
  }
}

// ---------------------------------------------------------------------------
// Kernel 2: recurrence + fused head. One block (one wave) per batch element.
// R6 diagnosis: the per-step CONDITIONAL xp load forced a conservative vmem
// wait on the serial chain every step (~500 cyc = the unexplained stall).
// Fix: NO vmem in the step loop. xp is preloaded in groups of 10 into
// double-buffered register arrays xA/xB (compile-time indices only), with
// 10 unconditional coalesced loads issued per group; the single vmcnt wait
// per group is covered by ~10 steps of compute.
// Step body itself is R4's proven bpermute broadcast (h register-resident).
// ---------------------------------------------------------------------------
__global__ __launch_bounds__(64, 1) void rnn_kernel(
    const float* __restrict__ xp, const float* __restrict__ W_hh,
    const float* __restrict__ fc_w, const float* __restrict__ fc_b,
    float* __restrict__ y) {
  __shared__ float hist[CC][68];
  const int b = blockIdx.x;
  const int lane = threadIdx.x;

  float W[64];
  float h = 0.f;  // lane i owns h[i]; carried in-register across segments

  for (int s = 0; s < SS; ++s) {
    const float* wr = W_hh + ((size_t)s * HH + lane) * HH;
#pragma unroll
    for (int j = 0; j < 64; j += 4) {
      float4 v = *(const float4*)(wr + j);
      W[j] = 2.f * v.x; W[j + 1] = 2.f * v.y;
      W[j + 2] = 2.f * v.z; W[j + 3] = 2.f * v.w;
    }
    const float* xps = xp + ((size_t)b * TT + s * CC) * HH + lane;

    float xA[10], xB[10];
    // prologue: preload steps 0..9 (10 coalesced, unconditional loads)
#pragma unroll
    for (int u = 0; u < 10; ++u) xA[u] = xps[u * HH];

    for (int gg = 0; gg < 5; ++gg) {
      const int base = gg * 20;

      // ---- half-group 1: prefetch base+10..base+19 into xB, compute from xA
#pragma unroll
      for (int u = 0; u < 10; ++u) xB[u] = xps[(base + 10 + u) * HH];
#pragma unroll
      for (int u = 0; u < 10; ++u) {
        const int c = base + u;
        const int hu = __float_as_int(h);
        float a0 = xA[u], a1 = 0.f, a2 = 0.f, a3 = 0.f;
#pragma unroll
        for (int j = 0; j < 64; j += 4) {
          float h0 = __int_as_float(__builtin_amdgcn_ds_bpermute((j + 0) * 4, hu));
          float h1 = __int_as_float(__builtin_amdgcn_ds_bpermute((j + 1) * 4, hu));
          float h2 = __int_as_float(__builtin_amdgcn_ds_bpermute((j + 2) * 4, hu));
          float h3 = __int_as_float(__builtin_amdgcn_ds_bpermute((j + 3) * 4, hu));
          a0 += W[j + 0] * h0;
          a1 += W[j + 1] * h1;
          a2 += W[j + 2] * h2;
          a3 += W[j + 3] * h3;
        }
        float z2 = (a0 + a1) + (a2 + a3);  // = 2z (prescaled)
        float e = __expf(z2);
        h = 1.f - 2.f * __builtin_amdgcn_rcpf(e + 1.f);
        hist[c][lane] = h;
      }

      // ---- half-group 2: prefetch base+20..base+29 into xA (clamped at
      // segment end; clamp is uniform scalar math, off the chain),
      // compute from xB
#pragma unroll
      for (int u = 0; u < 10; ++u) {
        int cp = base + 20 + u;
        if (cp > CC - 1) cp = CC - 1;  // last group: dummy (unused) reload
        xA[u] = xps[cp * HH];
      }
#pragma unroll
      for (int u = 0; u < 10; ++u) {
        const int c = base + 10 + u;
        const int hu = __float_as_int(h);
        float a0 = xB[u], a1 = 0.f, a2 = 0.f, a3 = 0.f;
#pragma unroll
        for (int j = 0; j < 64; j += 4) {
          float h0 = __int_as_float(__builtin_amdgcn_ds_bpermute((j + 0) * 4, hu));
          float h1 = __int_as_float(__builtin_amdgcn_ds_bpermute((j + 1) * 4, hu));
          float h2 = __int_as_float(__builtin_amdgcn_ds_bpermute((j + 2) * 4, hu));
          float h3 = __int_as_float(__builtin_amdgcn_ds_bpermute((j + 3) * 4, hu));
          a0 += W[j + 0] * h0;
          a1 += W[j + 1] * h1;
          a2 += W[j + 2] * h2;
          a3 += W[j + 3] * h3;
        }
        float z2 = (a0 + a1) + (a2 + a3);
        float e = __expf(z2);
        h = 1.f - 2.f * __builtin_amdgcn_rcpf(e + 1.f);
        hist[c][lane] = h;
      }
    }

    // fused head for this segment: lane l -> y[b, s*CC + l]
    const float fb = fc_b[s];
    const float* fw = fc_w + s * HH;  // wave-uniform -> scalar loads
#pragma unroll
    for (int base = 0; base < CC; base += 64) {
      int l = base + lane;
      if (l < CC) {
        float z = fb;
#pragma unroll
        for (int i = 0; i < 64; i += 4) {
          float4 hv = *(const float4*)&hist[l][i];
          z += hv.x * fw[i] + hv.y * fw[i + 1] + hv.z * fw[i + 2] +
               hv.w * fw[i + 3];
        }
        y[(size_t)b * TT + s * CC + l] =
            __builtin_amdgcn_rcpf(1.f + __expf(-z));
      }
    }
  }
}

extern "C" void kernel_launch(void* const* d_in, const int* in_sizes, int n_in,
                              void* d_out, int out_size, void* d_ws,
                              size_t ws_size, hipStream_t stream) {
  const float* x    = (const float*)d_in[0];
  const float* W_ih = (const float*)d_in[1];
  const float* W_hh = (const float*)d_in[2];
  const float* b_ih = (const float*)d_in[3];
  const float* b_hh = (const float*)d_in[4];
  const float* fc_w = (const float*)d_in[5];
  const float* fc_b = (const float*)d_in[6];
  float* y  = (float*)d_out;
  float* xp = (float*)d_ws;  // [B][T][H] fp32 = 65.5 MB

  proj_kernel<<<dim3(400, 10), 256, 0, stream>>>(x, W_ih, b_ih, b_hh, xp);
  rnn_kernel<<<256, 64, 0, stream>>>(xp, W_hh, fc_w, fc_b, y);
}

// Round 8
// 428.365 us; speedup vs baseline: 6.4954x; 1.0397x over previous
//
#include <hip/hip_runtime.h>
#include <cstdint>

#define BB 256
#define TT 1000
#define DD 256
#define SS 10
#define HH 64
#define CC 100

typedef float f32x4 __attribute__((ext_vector_type(4)));

// ---------------------------------------------------------------------------
// Kernel 1: input projection  xp[b,t,h] = 2*(x . W_ih + b_ih + b_hh)
// (unchanged from R7)
// ---------------------------------------------------------------------------
__global__ __launch_bounds__(256) void proj_kernel(
    const float* __restrict__ x, const float* __restrict__ W_ih,
    const float* __restrict__ b_ih, const float* __restrict__ b_hh,
    float* __restrict__ xp) {
  __shared__ float As[64][68];
  __shared__ float Bs[64][68];
  const int s = blockIdx.y;
  const int r0 = blockIdx.x * 64;
  const int tid = threadIdx.x;
  const int ty = tid >> 4, tx = tid & 15;
  const int ty4 = ty * 4, tx4 = tx * 4;
  float acc[4][4] = {{0.f, 0.f, 0.f, 0.f}};

  for (int kc = 0; kc < 4; ++kc) {
#pragma unroll
    for (int m = 0; m < 4; ++m) {
      int f = m * 256 + tid;
      int row = f >> 4, kq = f & 15;
      int r = r0 + row;
      int b = r / CC, c = r - b * CC;
      const float4 av = *(const float4*)(
          x + ((size_t)b * TT + s * CC + c) * DD + kc * 64 + kq * 4);
      *(float4*)&As[row][kq * 4] = av;
      const float4 wv = *(const float4*)(
          W_ih + ((size_t)s * HH + row) * DD + kc * 64 + kq * 4);
      *(float4*)&Bs[row][kq * 4] = wv;
    }
    __syncthreads();
#pragma unroll 4
    for (int k = 0; k < 64; k += 4) {
      float4 a[4], w[4];
#pragma unroll
      for (int i = 0; i < 4; ++i) a[i] = *(const float4*)&As[ty4 + i][k];
#pragma unroll
      for (int j = 0; j < 4; ++j) w[j] = *(const float4*)&Bs[tx4 + j][k];
#pragma unroll
      for (int i = 0; i < 4; ++i)
#pragma unroll
        for (int j = 0; j < 4; ++j)
          acc[i][j] += a[i].x * w[j].x + a[i].y * w[j].y +
                       a[i].z * w[j].z + a[i].w * w[j].w;
    }
    __syncthreads();
  }

  const float4 b1 = *(const float4*)(b_ih + s * HH + tx4);
  const float4 b2 = *(const float4*)(b_hh + s * HH + tx4);
#pragma unroll
  for (int i = 0; i < 4; ++i) {
    int r = r0 + ty4 + i;
    int b = r / CC, c = r - b * CC;
    float4 o;
    o.x = 2.f * (acc[i][0] + b1.x + b2.x);
    o.y = 2.f * (acc[i][1] + b1.y + b2.y);
    o.z = 2.f * (acc[i][2] + b1.z + b2.z);
    o.w = 2.f * (acc[i][3] + b1.w + b2.w);
    *(float4*)(xp + ((size_t)b * TT + s * CC + c) * HH + tx4) = o;
  }
}

// ---------------------------------------------------------------------------
// Kernel 2: recurrence + fused head. One block = one wave per batch element.
// R7 post-mortem: step was DS-issue-bound (64 bpermute x ~11cyc = ~700cyc).
// Now: 17 DS ops/step (1 ds_write_b32 + 16 uniform-addr ds_read_b128),
// hand-scheduled: all reads issued up front (volatile asm, forced-live
// outputs), then staggered counted waits lgkmcnt(12/8/4/0), each followed by
// sched_barrier(0) (rule: hipcc hoists reg-only ops past asm waitcnt), each
// unlocking 16 FMAs. In-order DS queue makes the counted waits exact.
// ---------------------------------------------------------------------------
#define DS_READ_G(R0, R1, R2, R3, O0, O1, O2, O3, ADDR)                       \
  asm volatile("ds_read_b128 %0, %4 offset:" O0 "\n\t"                        \
               "ds_read_b128 %1, %4 offset:" O1 "\n\t"                        \
               "ds_read_b128 %2, %4 offset:" O2 "\n\t"                        \
               "ds_read_b128 %3, %4 offset:" O3                               \
               : "=&v"(R0), "=&v"(R1), "=&v"(R2), "=&v"(R3)                   \
               : "v"(ADDR)                                                    \
               : "memory")

#define WAITG(N)                                                              \
  asm volatile("s_waitcnt lgkmcnt(" #N ")" ::: "memory");                     \
  __builtin_amdgcn_sched_barrier(0)

#define FMAG(g, R0, R1, R2, R3)                                               \
  a0 += W[16*g+ 0]*R0.x; a1 += W[16*g+ 1]*R0.y;                               \
  a2 += W[16*g+ 2]*R0.z; a3 += W[16*g+ 3]*R0.w;                               \
  a0 += W[16*g+ 4]*R1.x; a1 += W[16*g+ 5]*R1.y;                               \
  a2 += W[16*g+ 6]*R1.z; a3 += W[16*g+ 7]*R1.w;                               \
  a0 += W[16*g+ 8]*R2.x; a1 += W[16*g+ 9]*R2.y;                               \
  a2 += W[16*g+10]*R2.z; a3 += W[16*g+11]*R2.w;                               \
  a0 += W[16*g+12]*R3.x; a1 += W[16*g+13]*R3.y;                               \
  a2 += W[16*g+14]*R3.z; a3 += W[16*g+15]*R3.w;

#define STEP(c_, xv_) {                                                       \
  const int cp_ = ((c_) == 0) ? (CC - 1) : ((c_) - 1);                        \
  const uint32_t ra_ = hb + (uint32_t)(cp_ * 272);                            \
  f32x4 r0,r1,r2,r3,r4,r5,r6,r7,r8,r9,r10,r11,r12,r13,r14,r15;                \
  DS_READ_G(r0, r1, r2, r3,    "0",  "16",  "32",  "48", ra_);                \
  DS_READ_G(r4, r5, r6, r7,   "64",  "80",  "96", "112", ra_);                \
  DS_READ_G(r8, r9, r10,r11, "128", "144", "160", "176", ra_);                \
  DS_READ_G(r12,r13,r14,r15, "192", "208", "224", "240", ra_);                \
  float a0 = (xv_), a1 = 0.f, a2 = 0.f, a3 = 0.f;                             \
  WAITG(12);                                                                  \
  FMAG(0, r0, r1, r2, r3)                                                     \
  WAITG(8);                                                                   \
  FMAG(1, r4, r5, r6, r7)                                                     \
  WAITG(4);                                                                   \
  FMAG(2, r8, r9, r10, r11)                                                   \
  WAITG(0);                                                                   \
  FMAG(3, r12, r13, r14, r15)                                                 \
  float z2_ = (a0 + a1) + (a2 + a3);                                          \
  float e_ = __expf(z2_);                                                     \
  h = 1.f - 2.f * __builtin_amdgcn_rcpf(e_ + 1.f);                            \
  asm volatile("ds_write_b32 %0, %1"                                          \
               :: "v"(wb + (uint32_t)((c_) * 272)), "v"(h) : "memory");       \
}

__global__ __launch_bounds__(64, 1) void rnn_kernel(
    const float* __restrict__ xp, const float* __restrict__ W_hh,
    const float* __restrict__ fc_w, const float* __restrict__ fc_b,
    float* __restrict__ y) {
  __shared__ float hist[CC][68];
  const int b = blockIdx.x;
  const int lane = threadIdx.x;

  // LDS byte offset of hist (shared aperture is 4GB-aligned -> truncation of
  // the flat address yields the LDS offset)
  const uint32_t hb = (uint32_t)(uintptr_t)&hist[0][0];
  const uint32_t wb = hb + (uint32_t)(lane * 4);

  hist[CC - 1][lane] = 0.f;  // h0 = 0, read by s=0,c=0 (row CC-1)

  float W[64];
  float h = 0.f;
  for (int s = 0; s < SS; ++s) {
    const float* wr = W_hh + ((size_t)s * HH + lane) * HH;
#pragma unroll
    for (int j = 0; j < 64; j += 4) {
      float4 v = *(const float4*)(wr + j);
      W[j] = 2.f * v.x; W[j + 1] = 2.f * v.y;
      W[j + 2] = 2.f * v.z; W[j + 3] = 2.f * v.w;
    }
    const float* xps = xp + ((size_t)b * TT + s * CC) * HH + lane;

    float xA[10], xB[10];
#pragma unroll
    for (int u = 0; u < 10; ++u) xA[u] = xps[u * HH];

    for (int gg = 0; gg < 5; ++gg) {
      const int base = gg * 20;
      // prefetch next 10 into xB (loads pinned before step asms by clobbers)
#pragma unroll
      for (int u = 0; u < 10; ++u) xB[u] = xps[(base + 10 + u) * HH];
#pragma unroll
      for (int u = 0; u < 10; ++u) STEP(base + u, xA[u]);
      // prefetch following 10 into xA (clamped dummy on last group)
#pragma unroll
      for (int u = 0; u < 10; ++u) {
        int ci = base + 20 + u;
        if (ci > CC - 1) ci = CC - 1;
        xA[u] = xps[ci * HH];
      }
#pragma unroll
      for (int u = 0; u < 10; ++u) STEP(base + 10 + u, xB[u]);
    }

    // drain DS queue so C-level head reads see all asm writes
    asm volatile("s_waitcnt lgkmcnt(0)" ::: "memory");

    // fused head for this segment: lane l -> y[b, s*CC + l]
    const float fb = fc_b[s];
    const float* fw = fc_w + s * HH;
#pragma unroll
    for (int bse = 0; bse < CC; bse += 64) {
      int l = bse + lane;
      if (l < CC) {
        float z = fb;
#pragma unroll
        for (int i = 0; i < 64; i += 4) {
          float4 hv = *(const float4*)&hist[l][i];
          z += hv.x * fw[i] + hv.y * fw[i + 1] + hv.z * fw[i + 2] +
               hv.w * fw[i + 3];
        }
        y[(size_t)b * TT + s * CC + l] =
            __builtin_amdgcn_rcpf(1.f + __expf(-z));
      }
    }
  }
}

extern "C" void kernel_launch(void* const* d_in, const int* in_sizes, int n_in,
                              void* d_out, int out_size, void* d_ws,
                              size_t ws_size, hipStream_t stream) {
  const float* x    = (const float*)d_in[0];
  const float* W_ih = (const float*)d_in[1];
  const float* W_hh = (const float*)d_in[2];
  const float* b_ih = (const float*)d_in[3];
  const float* b_hh = (const float*)d_in[4];
  const float* fc_w = (const float*)d_in[5];
  const float* fc_b = (const float*)d_in[6];
  float* y  = (float*)d_out;
  float* xp = (float*)d_ws;  // [B][T][H] fp32 = 65.5 MB

  proj_kernel<<<dim3(400, 10), 256, 0, stream>>>(x, W_ih, b_ih, b_hh, xp);
  rnn_kernel<<<256, 64, 0, stream>>>(xp, W_hh, fc_w, fc_b, y);
}